// Round 1
// baseline (1956.461 us; speedup 1.0000x reference)
//
#include <hip/hip_runtime.h>
#include <math.h>

#define BSZ 16
#define NN  1024
#define DD  128
#define HH  8

// ---------------- K1: c = F_c + timestep_emb(t, N) broadcast over D -------
__global__ void k_embed(const float* __restrict__ F_c, const int* __restrict__ t,
                        float* __restrict__ c) {
    int idx = blockIdx.x * blockDim.x + threadIdx.x;   // over BSZ*NN*DD = 2M
    int n = (idx >> 7) & (NN - 1);
    int b = idx >> 17;
    float tv = (float)t[b];
    int j = n & 511;
    // freqs[j] = exp(-j * log(1000)/511)
    float freq = expf(-(float)j * 0.013518112092919054f);
    float e = tv * freq;
    float emb = (n < 512) ? sinf(e) : cosf(e);
    c[idx] = F_c[idx] + emb;
}

// ---------------- K2: QKV projection. Cin[M=16384,128] @ W[128,1024] + bias,
// output in head-major layout out[b][h][n][d], scaled by `scale`.
__global__ void k_proj_qkv(const float* __restrict__ Cin, const float* __restrict__ W,
                           const float* __restrict__ bias, float* __restrict__ Out,
                           float scale) {
    __shared__ float As[16][65];    // As[k][m]
    __shared__ float Bsh[16][68];   // Bsh[k][n]
    int tid = threadIdx.x;
    int tx = tid & 15, ty = tid >> 4;
    int m0 = blockIdx.x * 64;
    int n0 = blockIdx.y * 64;
    float acc[4][4] = {};
    for (int k0 = 0; k0 < 128; k0 += 16) {
        {
            int row = tid >> 2;
            int k4 = (tid & 3) * 4;
            float4 a4 = *(const float4*)(Cin + (size_t)(m0 + row) * 128 + k0 + k4);
            As[k4 + 0][row] = a4.x; As[k4 + 1][row] = a4.y;
            As[k4 + 2][row] = a4.z; As[k4 + 3][row] = a4.w;
        }
        {
            int kk = tid >> 4, c4 = (tid & 15) * 4;
            float4 b4 = *(const float4*)(W + (size_t)(k0 + kk) * 1024 + n0 + c4);
            *(float4*)(&Bsh[kk][c4]) = b4;
        }
        __syncthreads();
#pragma unroll
        for (int kk = 0; kk < 16; ++kk) {
            float a[4], bb[4];
#pragma unroll
            for (int i = 0; i < 4; i++) a[i] = As[kk][ty * 4 + i];
#pragma unroll
            for (int j = 0; j < 4; j++) bb[j] = Bsh[kk][tx * 4 + j];
#pragma unroll
            for (int i = 0; i < 4; i++)
#pragma unroll
                for (int j = 0; j < 4; j++) acc[i][j] += a[i] * bb[j];
        }
        __syncthreads();
    }
#pragma unroll
    for (int i = 0; i < 4; i++) {
        int m = m0 + ty * 4 + i;
        int b = m >> 10, n = m & 1023;
#pragma unroll
        for (int j = 0; j < 4; j++) {
            int col = n0 + tx * 4 + j;
            int h = col >> 7, d = col & 127;
            Out[(((size_t)(b * HH + h)) * NN + n) * DD + d] = (acc[i][j] + bias[col]) * scale;
        }
    }
}

// ---------------- K3: flash attention per (b,h). Q pre-scaled by 1/sqrt(D).
// Writes ctx in-place over the Q buffer.
__global__ __launch_bounds__(256) void k_attn(const float* __restrict__ Qg,
                                              const float* __restrict__ Kg,
                                              const float* __restrict__ Vg,
                                              float* __restrict__ Og) {
    __shared__ float Qs[64][133];
    __shared__ float Ks[32][133];
    __shared__ float Vs[32][133];
    __shared__ float Ss[64][33];
    __shared__ float rowM[64], rowL[64], rowA[64];
    const int tid = threadIdx.x;
    const int tx = tid & 15, ty = tid >> 4;
    const int tileq = blockIdx.x & 15;
    const size_t bh = blockIdx.x >> 4;
    const float* Qp = Qg + bh * (NN * DD) + (size_t)tileq * 64 * DD;
    const float* Kp = Kg + bh * (NN * DD);
    const float* Vp = Vg + bh * (NN * DD);
    float* Op = Og + bh * (NN * DD) + (size_t)tileq * 64 * DD;

#pragma unroll
    for (int p = 0; p < 8; ++p) {       // 64x128 Q tile
        int idx = p * 1024 + tid * 4;
        int r = idx >> 7, cc = idx & 127;
        float4 q4 = *(const float4*)(Qp + (size_t)r * DD + cc);
        Qs[r][cc + 0] = q4.x; Qs[r][cc + 1] = q4.y;
        Qs[r][cc + 2] = q4.z; Qs[r][cc + 3] = q4.w;
    }
    if (tid < 64) { rowM[tid] = -1e30f; rowL[tid] = 0.f; }
    float o[4][8];
#pragma unroll
    for (int i = 0; i < 4; i++)
#pragma unroll
        for (int j = 0; j < 8; j++) o[i][j] = 0.f;
    __syncthreads();

    for (int kt = 0; kt < 32; ++kt) {
#pragma unroll
        for (int p = 0; p < 4; ++p) {   // 32x128 K and V tiles
            int idx = p * 1024 + tid * 4;
            int r = idx >> 7, cc = idx & 127;
            float4 k4 = *(const float4*)(Kp + (size_t)(kt * 32 + r) * DD + cc);
            Ks[r][cc + 0] = k4.x; Ks[r][cc + 1] = k4.y;
            Ks[r][cc + 2] = k4.z; Ks[r][cc + 3] = k4.w;
            float4 v4 = *(const float4*)(Vp + (size_t)(kt * 32 + r) * DD + cc);
            Vs[r][cc + 0] = v4.x; Vs[r][cc + 1] = v4.y;
            Vs[r][cc + 2] = v4.z; Vs[r][cc + 3] = v4.w;
        }
        __syncthreads();
        // S tile: rows 4ty..+3, cols 2tx..+1
        float s[4][2] = {};
#pragma unroll 4
        for (int k = 0; k < 128; ++k) {
            float a0 = Qs[ty * 4 + 0][k], a1 = Qs[ty * 4 + 1][k];
            float a2 = Qs[ty * 4 + 2][k], a3 = Qs[ty * 4 + 3][k];
            float b0 = Ks[tx * 2 + 0][k], b1 = Ks[tx * 2 + 1][k];
            s[0][0] += a0 * b0; s[0][1] += a0 * b1;
            s[1][0] += a1 * b0; s[1][1] += a1 * b1;
            s[2][0] += a2 * b0; s[2][1] += a2 * b1;
            s[3][0] += a3 * b0; s[3][1] += a3 * b1;
        }
#pragma unroll
        for (int i = 0; i < 4; i++) {
            Ss[ty * 4 + i][tx * 2 + 0] = s[i][0];
            Ss[ty * 4 + i][tx * 2 + 1] = s[i][1];
        }
        __syncthreads();
        // online softmax row stats: 4 lanes per row
        {
            int r = tid >> 2, l4 = tid & 3;
            float vals[8];
            float mx = -1e30f;
#pragma unroll
            for (int u = 0; u < 8; u++) { vals[u] = Ss[r][l4 * 8 + u]; mx = fmaxf(mx, vals[u]); }
            mx = fmaxf(mx, __shfl_xor(mx, 1));
            mx = fmaxf(mx, __shfl_xor(mx, 2));
            float mold = rowM[r];
            float mnew = fmaxf(mold, mx);
            float psum = 0.f;
#pragma unroll
            for (int u = 0; u < 8; u++) {
                float p = __expf(vals[u] - mnew);
                Ss[r][l4 * 8 + u] = p;
                psum += p;
            }
            psum += __shfl_xor(psum, 1);
            psum += __shfl_xor(psum, 2);
            if (l4 == 0) {
                float al = __expf(mold - mnew);
                rowA[r] = al;
                rowL[r] = rowL[r] * al + psum;
                rowM[r] = mnew;
            }
        }
        __syncthreads();
        // O = O*alpha + P @ V ; thread cols j*16+tx
#pragma unroll
        for (int i = 0; i < 4; i++) {
            float al = rowA[ty * 4 + i];
#pragma unroll
            for (int j = 0; j < 8; j++) o[i][j] *= al;
        }
#pragma unroll 8
        for (int kk = 0; kk < 32; ++kk) {
            float p0 = Ss[ty * 4 + 0][kk], p1 = Ss[ty * 4 + 1][kk];
            float p2 = Ss[ty * 4 + 2][kk], p3 = Ss[ty * 4 + 3][kk];
#pragma unroll
            for (int j = 0; j < 8; j++) {
                float vv = Vs[kk][j * 16 + tx];
                o[0][j] += p0 * vv; o[1][j] += p1 * vv;
                o[2][j] += p2 * vv; o[3][j] += p3 * vv;
            }
        }
        __syncthreads();
    }
#pragma unroll
    for (int i = 0; i < 4; i++) {
        int r = ty * 4 + i;
        float inv = 1.f / rowL[r];
#pragma unroll
        for (int j = 0; j < 8; j++)
            Op[(size_t)r * DD + j * 16 + tx] = o[i][j] * inv;
    }
}

// ---------------- K4: h = ctx @ Wo + bo. ctx in [b][h][n][d] layout, K=1024.
__global__ void k_proj_o(const float* __restrict__ Ctx, const float* __restrict__ Wo,
                         const float* __restrict__ bo, float* __restrict__ Hout) {
    __shared__ float As[16][65];
    __shared__ float Bsh[16][68];
    int tid = threadIdx.x, tx = tid & 15, ty = tid >> 4;
    int m0 = blockIdx.x * 64, n0 = blockIdx.y * 64;
    float acc[4][4] = {};
    for (int k0 = 0; k0 < 1024; k0 += 16) {
        {
            int row = tid >> 2;
            int k4 = (tid & 3) * 4;
            int m = m0 + row;
            int b = m >> 10, n = m & 1023;
            int kidx = k0 + k4;
            int h = kidx >> 7, din = kidx & 127;
            float4 a4 = *(const float4*)(Ctx + (((size_t)(b * HH + h)) * NN + n) * DD + din);
            As[k4 + 0][row] = a4.x; As[k4 + 1][row] = a4.y;
            As[k4 + 2][row] = a4.z; As[k4 + 3][row] = a4.w;
        }
        {
            int kk = tid >> 4, c4 = (tid & 15) * 4;
            float4 b4 = *(const float4*)(Wo + (size_t)(k0 + kk) * DD + n0 + c4);
            *(float4*)(&Bsh[kk][c4]) = b4;
        }
        __syncthreads();
#pragma unroll
        for (int kk = 0; kk < 16; ++kk) {
            float a[4], bb[4];
#pragma unroll
            for (int i = 0; i < 4; i++) a[i] = As[kk][ty * 4 + i];
#pragma unroll
            for (int j = 0; j < 4; j++) bb[j] = Bsh[kk][tx * 4 + j];
#pragma unroll
            for (int i = 0; i < 4; i++)
#pragma unroll
                for (int j = 0; j < 4; j++) acc[i][j] += a[i] * bb[j];
        }
        __syncthreads();
    }
#pragma unroll
    for (int i = 0; i < 4; i++)
#pragma unroll
        for (int j = 0; j < 4; j++) {
            int col = n0 + tx * 4 + j;
            Hout[(size_t)(m0 + ty * 4 + i) * DD + col] = acc[i][j] + bo[col];
        }
}

// ---------------- K5/K6: generic batched GEMM C = [relu](A @ B [+ bias])
__global__ void k_gemm(const float* __restrict__ A, const float* __restrict__ B,
                       const float* __restrict__ bias, float* __restrict__ C,
                       int Kd, int Ncols, long sA, long sB, long sC, int relu) {
    __shared__ float As[16][65];
    __shared__ float Bsh[16][68];
    const float* Ap = A + (size_t)blockIdx.z * sA;
    const float* Bp = B + (size_t)blockIdx.z * sB;
    float* Cp = C + (size_t)blockIdx.z * sC;
    int tid = threadIdx.x, tx = tid & 15, ty = tid >> 4;
    int m0 = blockIdx.x * 64, n0 = blockIdx.y * 64;
    float acc[4][4] = {};
    for (int k0 = 0; k0 < Kd; k0 += 16) {
        {
            int row = tid >> 2;
            int k4 = (tid & 3) * 4;
            float4 a4 = *(const float4*)(Ap + (size_t)(m0 + row) * Kd + k0 + k4);
            As[k4 + 0][row] = a4.x; As[k4 + 1][row] = a4.y;
            As[k4 + 2][row] = a4.z; As[k4 + 3][row] = a4.w;
        }
        {
            int kk = tid >> 4, c4 = (tid & 15) * 4;
            float4 b4 = *(const float4*)(Bp + (size_t)(k0 + kk) * Ncols + n0 + c4);
            *(float4*)(&Bsh[kk][c4]) = b4;
        }
        __syncthreads();
#pragma unroll
        for (int kk = 0; kk < 16; ++kk) {
            float a[4], bb[4];
#pragma unroll
            for (int i = 0; i < 4; i++) a[i] = As[kk][ty * 4 + i];
#pragma unroll
            for (int j = 0; j < 4; j++) bb[j] = Bsh[kk][tx * 4 + j];
#pragma unroll
            for (int i = 0; i < 4; i++)
#pragma unroll
                for (int j = 0; j < 4; j++) acc[i][j] += a[i] * bb[j];
        }
        __syncthreads();
    }
#pragma unroll
    for (int i = 0; i < 4; i++)
#pragma unroll
        for (int j = 0; j < 4; j++) {
            int col = n0 + tx * 4 + j;
            float v = acc[i][j] + (bias ? bias[col] : 0.f);
            if (relu) v = fmaxf(v, 0.f);
            Cp[(size_t)(m0 + ty * 4 + i) * Ncols + col] = v;
        }
}

// ---------------- K7: in-place row normalize (mean, unbiased std over D=128)
__global__ __launch_bounds__(64) void k_norm(float* __restrict__ F) {
    int row = blockIdx.x;
    int t = threadIdx.x;
    float x0 = F[(size_t)row * 128 + t];
    float x1 = F[(size_t)row * 128 + 64 + t];
    float sum = x0 + x1;
#pragma unroll
    for (int off = 32; off; off >>= 1) sum += __shfl_xor(sum, off);
    float mu = sum * (1.f / 128.f);
    float d0 = x0 - mu, d1 = x1 - mu;
    float sq = d0 * d0 + d1 * d1;
#pragma unroll
    for (int off = 32; off; off >>= 1) sq += __shfl_xor(sq, off);
    float sd = sqrtf(sq * (1.f / 127.f));
    float inv = 1.f / (sd + 1e-8f);
    F[(size_t)row * 128 + t] = d0 * inv;
    F[(size_t)row * 128 + 64 + t] = d1 * inv;
}

// ---------------- K8: out[b] = norm[b] @ norm[b]^T / 128
__global__ void k_corr(const float* __restrict__ Nrm, float* __restrict__ Out) {
    __shared__ float As[16][65];
    __shared__ float Bs2[16][65];
    int b = blockIdx.z;
    const float* Ap = Nrm + (size_t)b * NN * DD;
    float* Op = Out + (size_t)b * NN * NN;
    int tid = threadIdx.x, tx = tid & 15, ty = tid >> 4;
    int n0 = blockIdx.x * 64;   // output rows
    int m0 = blockIdx.y * 64;   // output cols
    float acc[4][4] = {};
    for (int k0 = 0; k0 < 128; k0 += 16) {
        int row = tid >> 2;
        int k4 = (tid & 3) * 4;
        float4 a4 = *(const float4*)(Ap + (size_t)(n0 + row) * DD + k0 + k4);
        As[k4 + 0][row] = a4.x; As[k4 + 1][row] = a4.y;
        As[k4 + 2][row] = a4.z; As[k4 + 3][row] = a4.w;
        float4 b4 = *(const float4*)(Ap + (size_t)(m0 + row) * DD + k0 + k4);
        Bs2[k4 + 0][row] = b4.x; Bs2[k4 + 1][row] = b4.y;
        Bs2[k4 + 2][row] = b4.z; Bs2[k4 + 3][row] = b4.w;
        __syncthreads();
#pragma unroll
        for (int kk = 0; kk < 16; ++kk) {
            float a[4], bb[4];
#pragma unroll
            for (int i = 0; i < 4; i++) a[i] = As[kk][ty * 4 + i];
#pragma unroll
            for (int j = 0; j < 4; j++) bb[j] = Bs2[kk][tx * 4 + j];
#pragma unroll
            for (int i = 0; i < 4; i++)
#pragma unroll
                for (int j = 0; j < 4; j++) acc[i][j] += a[i] * bb[j];
        }
        __syncthreads();
    }
#pragma unroll
    for (int i = 0; i < 4; i++)
#pragma unroll
        for (int j = 0; j < 4; j++)
            Op[(size_t)(n0 + ty * 4 + i) * NN + m0 + tx * 4 + j] = acc[i][j] * (1.f / 128.f);
}

extern "C" void kernel_launch(void* const* d_in, const int* in_sizes, int n_in,
                              void* d_out, int out_size, void* d_ws, size_t ws_size,
                              hipStream_t stream) {
    const float* A_t = (const float*)d_in[0];
    const float* F_c = (const float*)d_in[1];
    const int*   t   = (const int*)d_in[2];
    const float* Wq  = (const float*)d_in[3];
    const float* bq  = (const float*)d_in[4];
    const float* Wk  = (const float*)d_in[5];
    const float* bk  = (const float*)d_in[6];
    const float* Wv  = (const float*)d_in[7];
    const float* bv  = (const float*)d_in[8];
    const float* Wo  = (const float*)d_in[9];
    const float* bo  = (const float*)d_in[10];
    const float* Wg  = (const float*)d_in[11];
    float* out = (float*)d_out;
    float* ws  = (float*)d_ws;

    // workspace layout (floats); buffers reused once dead:
    float* c    = ws;                    // [16,1024,128]  -> later h
    float* q    = ws + 2097152;          // [16,8,1024,128] -> ctx (in-place)
    float* kbuf = ws + 18874368;         // [16,8,1024,128] -> later hg
    float* vbuf = ws + 35651584;         // [16,8,1024,128] -> later feat/norm
    float* h    = c;
    float* hg   = kbuf;
    float* feat = vbuf;

    const float qscale = 0.08838834764831845f;   // 1/sqrt(128)

    k_embed<<<8192, 256, 0, stream>>>(F_c, t, c);
    k_proj_qkv<<<dim3(256, 16), 256, 0, stream>>>(c, Wq, bq, q,    qscale);
    k_proj_qkv<<<dim3(256, 16), 256, 0, stream>>>(c, Wk, bk, kbuf, 1.f);
    k_proj_qkv<<<dim3(256, 16), 256, 0, stream>>>(c, Wv, bv, vbuf, 1.f);
    k_attn<<<2048, 256, 0, stream>>>(q, kbuf, vbuf, q);
    k_proj_o<<<dim3(256, 2), 256, 0, stream>>>(q, Wo, bo, h);
    k_gemm<<<dim3(256, 2, 1), 256, 0, stream>>>(h, Wg, nullptr, hg, 128, 128, 0, 0, 0, 0);
    k_gemm<<<dim3(16, 2, 16), 256, 0, stream>>>(A_t, hg, nullptr, feat, 1024, 128,
                                                (long)NN * NN, (long)NN * DD, (long)NN * DD, 1);
    k_norm<<<16384, 64, 0, stream>>>(feat);
    k_corr<<<dim3(16, 16, 16), 256, 0, stream>>>(feat, out);
}

// Round 2
// 752.986 us; speedup vs baseline: 2.5983x; 2.5983x over previous
//
#include <hip/hip_runtime.h>
#include <math.h>

#define BSZ 16
#define NN  1024
#define DD  128
#define HH  8

typedef __attribute__((ext_vector_type(8))) short short8;
typedef __attribute__((ext_vector_type(4))) float f32x4;

__device__ inline unsigned short f2bf(float x) {
    union { float f; unsigned u; } v; v.f = x;
    unsigned r = (v.u + 0x7FFF + ((v.u >> 16) & 1)) >> 16;
    return (unsigned short)r;
}

// ---------------- K1: c = F_c + timestep_emb(t, N) broadcast over D -------
__global__ void k_embed(const float* __restrict__ F_c, const int* __restrict__ t,
                        float* __restrict__ c) {
    int idx = blockIdx.x * blockDim.x + threadIdx.x;   // over BSZ*NN*DD = 2M
    int n = (idx >> 7) & (NN - 1);
    int b = idx >> 17;
    float tv = (float)t[b];
    int j = n & 511;
    float freq = expf(-(float)j * 0.013518112092919054f);
    float e = tv * freq;
    float emb = (n < 512) ? sinf(e) : cosf(e);
    c[idx] = F_c[idx] + emb;
}

// ---------------- K2: QKV projection -> bf16 head-major output.
// mode 0: Out[((b*H+h)*N+n)*D+d] (Q/K).  mode 1: Out[((b*H+h)*D+d)*N+n] (V^T).
__global__ void k_proj_qkv_bf16(const float* __restrict__ Cin, const float* __restrict__ W,
                                const float* __restrict__ bias, unsigned short* __restrict__ Out,
                                float scale, int transposeV) {
    __shared__ float As[16][65];    // As[k][m]
    __shared__ float Bsh[16][68];   // Bsh[k][n]
    int tid = threadIdx.x;
    int tx = tid & 15, ty = tid >> 4;
    int m0 = blockIdx.x * 64;
    int n0 = blockIdx.y * 64;
    float acc[4][4] = {};
    for (int k0 = 0; k0 < 128; k0 += 16) {
        {
            int row = tid >> 2;
            int k4 = (tid & 3) * 4;
            float4 a4 = *(const float4*)(Cin + (size_t)(m0 + row) * 128 + k0 + k4);
            As[k4 + 0][row] = a4.x; As[k4 + 1][row] = a4.y;
            As[k4 + 2][row] = a4.z; As[k4 + 3][row] = a4.w;
        }
        {
            int kk = tid >> 4, c4 = (tid & 15) * 4;
            float4 b4 = *(const float4*)(W + (size_t)(k0 + kk) * 1024 + n0 + c4);
            *(float4*)(&Bsh[kk][c4]) = b4;
        }
        __syncthreads();
#pragma unroll
        for (int kk = 0; kk < 16; ++kk) {
            float a[4], bb[4];
#pragma unroll
            for (int i = 0; i < 4; i++) a[i] = As[kk][ty * 4 + i];
#pragma unroll
            for (int j = 0; j < 4; j++) bb[j] = Bsh[kk][tx * 4 + j];
#pragma unroll
            for (int i = 0; i < 4; i++)
#pragma unroll
                for (int j = 0; j < 4; j++) acc[i][j] += a[i] * bb[j];
        }
        __syncthreads();
    }
#pragma unroll
    for (int i = 0; i < 4; i++) {
        int m = m0 + ty * 4 + i;
        int b = m >> 10, n = m & 1023;
#pragma unroll
        for (int j = 0; j < 4; j++) {
            int col = n0 + tx * 4 + j;
            int h = col >> 7, d = col & 127;
            unsigned short val = f2bf((acc[i][j] + bias[col]) * scale);
            if (transposeV)
                Out[(((size_t)(b * HH + h)) * DD + d) * NN + n] = val;
            else
                Out[(((size_t)(b * HH + h)) * NN + n) * DD + d] = val;
        }
    }
}

// ---------------- K3: bf16-MFMA flash attention per (b,h).
// Q pre-scaled bf16 [bh][n][d]; K bf16 [bh][n][d]; V bf16 transposed [bh][d][n].
// Output ctx fp32 [bh][n][d].
__global__ __launch_bounds__(256) void k_attn_mfma(const unsigned short* __restrict__ Qg,
                                                   const unsigned short* __restrict__ Kg,
                                                   const unsigned short* __restrict__ Vtg,
                                                   float* __restrict__ Og) {
    __shared__ unsigned short Qs[64][136];   // pad 128->136 (stride 68 dw: 2-way max)
    __shared__ unsigned short Ks[64][136];
    __shared__ unsigned short Vt[128][72];   // [d][key], pad 64->72 (36 dw)
    __shared__ unsigned short Sp[4][16][72]; // per-wave P, bf16

    const int tid  = threadIdx.x;
    const int wave = tid >> 6;
    const int lane = tid & 63;
    const int n16  = lane & 15;
    const int quad = lane >> 4;

    // XCD-friendly remap: bh constant per XCD slot, tiles temporally clustered
    const int g = blockIdx.x;
    const int bh = (g & 7) + 8 * (g >> 7);
    const int tileq = (g >> 3) & 15;

    const unsigned short* Qp  = Qg  + (size_t)bh * NN * DD + (size_t)tileq * 64 * DD;
    const unsigned short* Kp  = Kg  + (size_t)bh * NN * DD;
    const unsigned short* Vp  = Vtg + (size_t)bh * NN * DD;   // [d][n]
    float* Op = Og + (size_t)bh * NN * DD + (size_t)tileq * 64 * DD;

    // stage Q tile (64x128 bf16)
#pragma unroll
    for (int p = 0; p < 4; ++p) {
        int idx = tid + p * 256;          // 1024 chunks of 8 bf16
        int r = idx >> 4, ch = idx & 15;
        uint4 v = *(const uint4*)(Qp + (size_t)r * DD + ch * 8);
        *(uint4*)&Qs[r][ch * 8] = v;
    }

    float mrun[4], lrun[4];
#pragma unroll
    for (int i = 0; i < 4; i++) { mrun[i] = -1e30f; lrun[i] = 0.f; }
    f32x4 O[8];
#pragma unroll
    for (int i = 0; i < 8; i++) O[i] = (f32x4){0.f, 0.f, 0.f, 0.f};

    short8 qf[4];
    bool qloaded = false;

    for (int kt = 0; kt < 16; ++kt) {
        __syncthreads();   // previous compute done / Qs staged
        // stage K tile (64x128) and V^T tile (128x64)
#pragma unroll
        for (int p = 0; p < 4; ++p) {
            int idx = tid + p * 256;
            int r = idx >> 4, ch = idx & 15;
            uint4 v = *(const uint4*)(Kp + (size_t)(kt * 64 + r) * DD + ch * 8);
            *(uint4*)&Ks[r][ch * 8] = v;
        }
#pragma unroll
        for (int p = 0; p < 4; ++p) {
            int idx = tid + p * 256;
            int r = idx >> 3, ch = idx & 7;   // r: d-row 0..127, ch: key chunk
            uint4 v = *(const uint4*)(Vp + (size_t)r * NN + kt * 64 + ch * 8);
            *(uint4*)&Vt[r][ch * 8] = v;
        }
        __syncthreads();

        if (!qloaded) {
#pragma unroll
            for (int dc = 0; dc < 4; ++dc)
                qf[dc] = *(const short8*)&Qs[wave * 16 + n16][dc * 32 + quad * 8];
            qloaded = true;
        }

        // S = Q K^T  (16 rows x 64 keys per wave)
        f32x4 S[4];
#pragma unroll
        for (int kc = 0; kc < 4; ++kc) {
            f32x4 acc = (f32x4){0.f, 0.f, 0.f, 0.f};
#pragma unroll
            for (int dc = 0; dc < 4; ++dc) {
                short8 kf = *(const short8*)&Ks[kc * 16 + n16][dc * 32 + quad * 8];
                acc = __builtin_amdgcn_mfma_f32_16x16x32_bf16(qf[dc], kf, acc, 0, 0, 0);
            }
            S[kc] = acc;
        }

        // online softmax (rows r = quad*4+reg; 16 lanes per quad share rows)
        float mnew[4], alpha[4], psum[4];
#pragma unroll
        for (int reg = 0; reg < 4; ++reg) {
            float mx = fmaxf(fmaxf(S[0][reg], S[1][reg]), fmaxf(S[2][reg], S[3][reg]));
            mx = fmaxf(mx, __shfl_xor(mx, 1));
            mx = fmaxf(mx, __shfl_xor(mx, 2));
            mx = fmaxf(mx, __shfl_xor(mx, 4));
            mx = fmaxf(mx, __shfl_xor(mx, 8));
            mnew[reg] = fmaxf(mrun[reg], mx);
            alpha[reg] = __expf(mrun[reg] - mnew[reg]);
            mrun[reg] = mnew[reg];
            psum[reg] = 0.f;
        }
#pragma unroll
        for (int kc = 0; kc < 4; ++kc)
#pragma unroll
            for (int reg = 0; reg < 4; ++reg) {
                float p = __expf(S[kc][reg] - mnew[reg]);
                S[kc][reg] = p;
                psum[reg] += p;
            }
#pragma unroll
        for (int reg = 0; reg < 4; ++reg) {
            float ps = psum[reg];
            ps += __shfl_xor(ps, 1);
            ps += __shfl_xor(ps, 2);
            ps += __shfl_xor(ps, 4);
            ps += __shfl_xor(ps, 8);
            lrun[reg] = lrun[reg] * alpha[reg] + ps;
        }
        // write P (bf16) to per-wave LDS
#pragma unroll
        for (int kc = 0; kc < 4; ++kc)
#pragma unroll
            for (int reg = 0; reg < 4; ++reg)
                Sp[wave][quad * 4 + reg][kc * 16 + n16] = f2bf(S[kc][reg]);
        asm volatile("s_waitcnt lgkmcnt(0)" ::: "memory");   // wave-local LDS fence

        // O = O*alpha + P @ V
#pragma unroll
        for (int dc = 0; dc < 8; ++dc)
#pragma unroll
            for (int reg = 0; reg < 4; ++reg) O[dc][reg] *= alpha[reg];
#pragma unroll
        for (int kchunk = 0; kchunk < 2; ++kchunk) {
            short8 pf = *(const short8*)&Sp[wave][n16][kchunk * 32 + quad * 8];
#pragma unroll
            for (int dc = 0; dc < 8; ++dc) {
                short8 vf = *(const short8*)&Vt[dc * 16 + n16][kchunk * 32 + quad * 8];
                O[dc] = __builtin_amdgcn_mfma_f32_16x16x32_bf16(pf, vf, O[dc], 0, 0, 0);
            }
        }
    }

    // epilogue: ctx = O / l
#pragma unroll
    for (int reg = 0; reg < 4; ++reg) {
        float inv = 1.f / lrun[reg];
        int r = wave * 16 + quad * 4 + reg;
#pragma unroll
        for (int dc = 0; dc < 8; ++dc)
            Op[(size_t)r * DD + dc * 16 + n16] = O[dc][reg] * inv;
    }
}

// ---------------- K4: h = ctx @ Wo + bo. ctx in [b][h][n][d] layout, K=1024.
__global__ void k_proj_o(const float* __restrict__ Ctx, const float* __restrict__ Wo,
                         const float* __restrict__ bo, float* __restrict__ Hout) {
    __shared__ float As[16][65];
    __shared__ float Bsh[16][68];
    int tid = threadIdx.x, tx = tid & 15, ty = tid >> 4;
    int m0 = blockIdx.x * 64, n0 = blockIdx.y * 64;
    float acc[4][4] = {};
    for (int k0 = 0; k0 < 1024; k0 += 16) {
        {
            int row = tid >> 2;
            int k4 = (tid & 3) * 4;
            int m = m0 + row;
            int b = m >> 10, n = m & 1023;
            int kidx = k0 + k4;
            int h = kidx >> 7, din = kidx & 127;
            float4 a4 = *(const float4*)(Ctx + (((size_t)(b * HH + h)) * NN + n) * DD + din);
            As[k4 + 0][row] = a4.x; As[k4 + 1][row] = a4.y;
            As[k4 + 2][row] = a4.z; As[k4 + 3][row] = a4.w;
        }
        {
            int kk = tid >> 4, c4 = (tid & 15) * 4;
            float4 b4 = *(const float4*)(Wo + (size_t)(k0 + kk) * DD + n0 + c4);
            *(float4*)(&Bsh[kk][c4]) = b4;
        }
        __syncthreads();
#pragma unroll
        for (int kk = 0; kk < 16; ++kk) {
            float a[4], bb[4];
#pragma unroll
            for (int i = 0; i < 4; i++) a[i] = As[kk][ty * 4 + i];
#pragma unroll
            for (int j = 0; j < 4; j++) bb[j] = Bsh[kk][tx * 4 + j];
#pragma unroll
            for (int i = 0; i < 4; i++)
#pragma unroll
                for (int j = 0; j < 4; j++) acc[i][j] += a[i] * bb[j];
        }
        __syncthreads();
    }
#pragma unroll
    for (int i = 0; i < 4; i++)
#pragma unroll
        for (int j = 0; j < 4; j++) {
            int col = n0 + tx * 4 + j;
            Hout[(size_t)(m0 + ty * 4 + i) * DD + col] = acc[i][j] + bo[col];
        }
}

// ---------------- K5/K6: generic batched GEMM C = [relu](A @ B [+ bias])
__global__ void k_gemm(const float* __restrict__ A, const float* __restrict__ B,
                       const float* __restrict__ bias, float* __restrict__ C,
                       int Kd, int Ncols, long sA, long sB, long sC, int relu) {
    __shared__ float As[16][65];
    __shared__ float Bsh[16][68];
    const float* Ap = A + (size_t)blockIdx.z * sA;
    const float* Bp = B + (size_t)blockIdx.z * sB;
    float* Cp = C + (size_t)blockIdx.z * sC;
    int tid = threadIdx.x, tx = tid & 15, ty = tid >> 4;
    int m0 = blockIdx.x * 64, n0 = blockIdx.y * 64;
    float acc[4][4] = {};
    for (int k0 = 0; k0 < Kd; k0 += 16) {
        {
            int row = tid >> 2;
            int k4 = (tid & 3) * 4;
            float4 a4 = *(const float4*)(Ap + (size_t)(m0 + row) * Kd + k0 + k4);
            As[k4 + 0][row] = a4.x; As[k4 + 1][row] = a4.y;
            As[k4 + 2][row] = a4.z; As[k4 + 3][row] = a4.w;
        }
        {
            int kk = tid >> 4, c4 = (tid & 15) * 4;
            float4 b4 = *(const float4*)(Bp + (size_t)(k0 + kk) * Ncols + n0 + c4);
            *(float4*)(&Bsh[kk][c4]) = b4;
        }
        __syncthreads();
#pragma unroll
        for (int kk = 0; kk < 16; ++kk) {
            float a[4], bb[4];
#pragma unroll
            for (int i = 0; i < 4; i++) a[i] = As[kk][ty * 4 + i];
#pragma unroll
            for (int j = 0; j < 4; j++) bb[j] = Bsh[kk][tx * 4 + j];
#pragma unroll
            for (int i = 0; i < 4; i++)
#pragma unroll
                for (int j = 0; j < 4; j++) acc[i][j] += a[i] * bb[j];
        }
        __syncthreads();
    }
#pragma unroll
    for (int i = 0; i < 4; i++)
#pragma unroll
        for (int j = 0; j < 4; j++) {
            int col = n0 + tx * 4 + j;
            float v = acc[i][j] + (bias ? bias[col] : 0.f);
            if (relu) v = fmaxf(v, 0.f);
            Cp[(size_t)(m0 + ty * 4 + i) * Ncols + col] = v;
        }
}

// ---------------- K7: in-place row normalize (mean, unbiased std over D=128)
__global__ __launch_bounds__(64) void k_norm(float* __restrict__ F) {
    int row = blockIdx.x;
    int t = threadIdx.x;
    float x0 = F[(size_t)row * 128 + t];
    float x1 = F[(size_t)row * 128 + 64 + t];
    float sum = x0 + x1;
#pragma unroll
    for (int off = 32; off; off >>= 1) sum += __shfl_xor(sum, off);
    float mu = sum * (1.f / 128.f);
    float d0 = x0 - mu, d1 = x1 - mu;
    float sq = d0 * d0 + d1 * d1;
#pragma unroll
    for (int off = 32; off; off >>= 1) sq += __shfl_xor(sq, off);
    float sd = sqrtf(sq * (1.f / 127.f));
    float inv = 1.f / (sd + 1e-8f);
    F[(size_t)row * 128 + t] = d0 * inv;
    F[(size_t)row * 128 + 64 + t] = d1 * inv;
}

// ---------------- K8: out[b] = norm[b] @ norm[b]^T / 128
__global__ void k_corr(const float* __restrict__ Nrm, float* __restrict__ Out) {
    __shared__ float As[16][65];
    __shared__ float Bs2[16][65];
    int b = blockIdx.z;
    const float* Ap = Nrm + (size_t)b * NN * DD;
    float* Op = Out + (size_t)b * NN * NN;
    int tid = threadIdx.x, tx = tid & 15, ty = tid >> 4;
    int n0 = blockIdx.x * 64;   // output rows
    int m0 = blockIdx.y * 64;   // output cols
    float acc[4][4] = {};
    for (int k0 = 0; k0 < 128; k0 += 16) {
        int row = tid >> 2;
        int k4 = (tid & 3) * 4;
        float4 a4 = *(const float4*)(Ap + (size_t)(n0 + row) * DD + k0 + k4);
        As[k4 + 0][row] = a4.x; As[k4 + 1][row] = a4.y;
        As[k4 + 2][row] = a4.z; As[k4 + 3][row] = a4.w;
        float4 b4 = *(const float4*)(Ap + (size_t)(m0 + row) * DD + k0 + k4);
        Bs2[k4 + 0][row] = b4.x; Bs2[k4 + 1][row] = b4.y;
        Bs2[k4 + 2][row] = b4.z; Bs2[k4 + 3][row] = b4.w;
        __syncthreads();
#pragma unroll
        for (int kk = 0; kk < 16; ++kk) {
            float a[4], bb[4];
#pragma unroll
            for (int i = 0; i < 4; i++) a[i] = As[kk][ty * 4 + i];
#pragma unroll
            for (int j = 0; j < 4; j++) bb[j] = Bs2[kk][tx * 4 + j];
#pragma unroll
            for (int i = 0; i < 4; i++)
#pragma unroll
                for (int j = 0; j < 4; j++) acc[i][j] += a[i] * bb[j];
        }
        __syncthreads();
    }
#pragma unroll
    for (int i = 0; i < 4; i++)
#pragma unroll
        for (int j = 0; j < 4; j++)
            Op[(size_t)(n0 + ty * 4 + i) * NN + m0 + tx * 4 + j] = acc[i][j] * (1.f / 128.f);
}

extern "C" void kernel_launch(void* const* d_in, const int* in_sizes, int n_in,
                              void* d_out, int out_size, void* d_ws, size_t ws_size,
                              hipStream_t stream) {
    const float* A_t = (const float*)d_in[0];
    const float* F_c = (const float*)d_in[1];
    const int*   t   = (const int*)d_in[2];
    const float* Wq  = (const float*)d_in[3];
    const float* bq  = (const float*)d_in[4];
    const float* Wk  = (const float*)d_in[5];
    const float* bk  = (const float*)d_in[6];
    const float* Wv  = (const float*)d_in[7];
    const float* bv  = (const float*)d_in[8];
    const float* Wo  = (const float*)d_in[9];
    const float* bo  = (const float*)d_in[10];
    const float* Wg  = (const float*)d_in[11];
    float* out = (float*)d_out;
    float* ws  = (float*)d_ws;

    // workspace layout (float offsets):
    float* c    = ws;                          // [16,1024,128] fp32 -> later h
    float* ctx  = ws + 2097152;                // [16,8,1024,128] fp32
    unsigned short* qb  = (unsigned short*)(ws + 18874368);  // bf16 [bh][n][d]
    unsigned short* kb  = (unsigned short*)(ws + 27262976);  // bf16 [bh][n][d]
    unsigned short* vtb = (unsigned short*)(ws + 35651584);  // bf16 [bh][d][n]
    float* hg   = ws + 44040192;               // [16,1024,128]
    float* feat = ws + 46137344;               // [16,1024,128]
    float* h    = c;

    const float qscale = 0.08838834764831845f;   // 1/sqrt(128)

    k_embed<<<8192, 256, 0, stream>>>(F_c, t, c);
    k_proj_qkv_bf16<<<dim3(256, 16), 256, 0, stream>>>(c, Wq, bq, qb,  qscale, 0);
    k_proj_qkv_bf16<<<dim3(256, 16), 256, 0, stream>>>(c, Wk, bk, kb,  1.f,    0);
    k_proj_qkv_bf16<<<dim3(256, 16), 256, 0, stream>>>(c, Wv, bv, vtb, 1.f,    1);
    k_attn_mfma<<<2048, 256, 0, stream>>>(qb, kb, vtb, ctx);
    k_proj_o<<<dim3(256, 2), 256, 0, stream>>>(ctx, Wo, bo, h);
    k_gemm<<<dim3(256, 2, 1), 256, 0, stream>>>(h, Wg, nullptr, hg, 128, 128, 0, 0, 0, 0);
    k_gemm<<<dim3(16, 2, 16), 256, 0, stream>>>(A_t, hg, nullptr, feat, 1024, 128,
                                                (long)NN * NN, (long)NN * DD, (long)NN * DD, 1);
    k_norm<<<16384, 64, 0, stream>>>(feat);
    k_corr<<<dim3(16, 16, 16), 256, 0, stream>>>(feat, out);
}

// Round 3
// 418.389 us; speedup vs baseline: 4.6762x; 1.7997x over previous
//
#include <hip/hip_runtime.h>
#include <math.h>

#define NN 1024
#define DD 128
#define HH 8

typedef __attribute__((ext_vector_type(8))) short short8;
typedef __attribute__((ext_vector_type(4))) float f32x4;

__device__ inline unsigned short f2bf(float x) {
    union { float f; unsigned u; } v; v.f = x;
    return (unsigned short)((v.u + 0x7FFF + ((v.u >> 16) & 1)) >> 16);
}
__device__ inline unsigned pack2(float a, float b) {
    return (unsigned)f2bf(a) | ((unsigned)f2bf(b) << 16);
}

// ---------------- weight prep: transpose fp32 [R][C] -> bf16 [C][R] ----------
__global__ __launch_bounds__(256) void k_prep_w(
    const float* __restrict__ Wq, const float* __restrict__ Wk, const float* __restrict__ Wv,
    const float* __restrict__ Wo, const float* __restrict__ Wg,
    unsigned short* WqT, unsigned short* WkT, unsigned short* WvT,
    unsigned short* WoT, unsigned short* WgT) {
    int id = blockIdx.x;
    const float* src; unsigned short* dst; int R, C, ti;
    if (id < 128)      { src = Wq; dst = WqT; R = 128;  C = 1024; ti = id; }
    else if (id < 256) { src = Wk; dst = WkT; R = 128;  C = 1024; ti = id - 128; }
    else if (id < 384) { src = Wv; dst = WvT; R = 128;  C = 1024; ti = id - 256; }
    else if (id < 512) { src = Wo; dst = WoT; R = 1024; C = 128;  ti = id - 384; }
    else               { src = Wg; dst = WgT; R = 128;  C = 128;  ti = id - 512; }
    int tc = C >> 5;
    int r0 = (ti / tc) << 5, c0 = (ti % tc) << 5;
    __shared__ float T[32][33];
    int tid = threadIdx.x;
    int r = tid >> 3, c4 = (tid & 7) << 2;
    float4 v = *(const float4*)&src[(size_t)(r0 + r) * C + c0 + c4];
    T[r][c4] = v.x; T[r][c4 + 1] = v.y; T[r][c4 + 2] = v.z; T[r][c4 + 3] = v.w;
    __syncthreads();
    int c = tid >> 3, r4 = (tid & 7) << 2;
    uint2 o;
    o.x = pack2(T[r4][c], T[r4 + 1][c]);
    o.y = pack2(T[r4 + 2][c], T[r4 + 3][c]);
    *(uint2*)&dst[(size_t)(c0 + c) * R + r0 + r4] = o;
}

// ---------------- K1: c = bf16(F_c + emb) ------------------------------------
__global__ __launch_bounds__(256) void k_embed(const float* __restrict__ F_c,
                                               const int* __restrict__ t,
                                               unsigned short* __restrict__ cb) {
    int gi = blockIdx.x * 256 + threadIdx.x;    // 262144 chunks of 8
    int row = gi >> 4, ch = gi & 15;
    int b = row >> 10, n = row & 1023;
    float tv = (float)t[b];
    int j = n & 511;
    float e = tv * expf(-(float)j * 0.013518112092919054f);
    float emb = (n < 512) ? sinf(e) : cosf(e);
    const float* src = F_c + (size_t)row * 128 + ch * 8;
    float4 a = *(const float4*)src;
    float4 c4 = *(const float4*)(src + 4);
    uint4 o;
    o.x = pack2(a.x + emb, a.y + emb);  o.y = pack2(a.z + emb, a.w + emb);
    o.z = pack2(c4.x + emb, c4.y + emb); o.w = pack2(c4.z + emb, c4.w + emb);
    *(uint4*)&cb[(size_t)row * 128 + ch * 8] = o;
}

// ---------------- generic K=128 MFMA GEMM, 128x128 tile ----------------------
// Out bf16: mode 0 -> [(b*bh_mul+head)][n][col]; mode 1 -> [(b*bh_mul+head)][col][n]
__global__ __launch_bounds__(256) void k_proj(const unsigned short* __restrict__ Ain,
                                              const unsigned short* __restrict__ WT,
                                              const float* __restrict__ bias,
                                              unsigned short* __restrict__ Out,
                                              float scale, int mode, int bh_mul) {
    __shared__ __align__(16) unsigned short sm[2 * 128 * 136];
    unsigned short* CT  = sm;               // [128][136]
    unsigned short* WTs = sm + 128 * 136;   // [128][136]
    int tid = threadIdx.x;
    int m0 = blockIdx.x * 128;
    int head = blockIdx.y;
    int w = tid >> 6, lane = tid & 63, n16 = lane & 15, quad = lane >> 4;
#pragma unroll
    for (int p = 0; p < 8; ++p) {
        int idx = tid + p * 256;
        int r = idx >> 4, ch = idx & 15;
        *(uint4*)&CT[r * 136 + ch * 8]  = *(const uint4*)&Ain[(size_t)(m0 + r) * 128 + ch * 8];
        *(uint4*)&WTs[r * 136 + ch * 8] = *(const uint4*)&WT[(size_t)(head * 128 + r) * 128 + ch * 8];
    }
    __syncthreads();
    int wr = (w >> 1) * 64, wc = (w & 1) * 64;
    f32x4 acc[4][4];
#pragma unroll
    for (int i = 0; i < 4; i++)
#pragma unroll
        for (int j = 0; j < 4; j++) acc[i][j] = (f32x4){0.f, 0.f, 0.f, 0.f};
#pragma unroll
    for (int kk = 0; kk < 4; ++kk) {
        short8 af[4], bf[4];
#pragma unroll
        for (int rb = 0; rb < 4; ++rb)
            af[rb] = *(const short8*)&CT[(wr + rb * 16 + n16) * 136 + kk * 32 + quad * 8];
#pragma unroll
        for (int cb = 0; cb < 4; ++cb)
            bf[cb] = *(const short8*)&WTs[(wc + cb * 16 + n16) * 136 + kk * 32 + quad * 8];
#pragma unroll
        for (int rb = 0; rb < 4; ++rb)
#pragma unroll
            for (int cb = 0; cb < 4; ++cb)
                acc[rb][cb] = __builtin_amdgcn_mfma_f32_16x16x32_bf16(af[rb], bf[cb], acc[rb][cb], 0, 0, 0);
    }
    __syncthreads();    // all frag reads done; reuse CT as bounce
#pragma unroll
    for (int rb = 0; rb < 4; ++rb)
#pragma unroll
        for (int cb = 0; cb < 4; ++cb) {
            int colb = wc + cb * 16 + n16;
            float bs = bias ? bias[head * 128 + colb] : 0.f;
#pragma unroll
            for (int reg = 0; reg < 4; ++reg) {
                int rowb = wr + rb * 16 + quad * 4 + reg;
                unsigned short val = f2bf((acc[rb][cb][reg] + bs) * scale);
                if (mode == 0) CT[rowb * 136 + colb] = val;
                else           CT[colb * 136 + rowb] = val;
            }
        }
    __syncthreads();
    int b = m0 >> 10, n0 = m0 & 1023;
    size_t base = (size_t)(b * bh_mul + head) * 131072;
    if (mode == 0) {
#pragma unroll
        for (int p = 0; p < 8; ++p) {
            int idx = tid + p * 256;
            int r = idx >> 4, ch = idx & 15;
            *(uint4*)&Out[base + (size_t)(n0 + r) * 128 + ch * 8] = *(const uint4*)&CT[r * 136 + ch * 8];
        }
    } else {
#pragma unroll
        for (int p = 0; p < 8; ++p) {
            int idx = tid + p * 256;
            int r = idx >> 4, ch = idx & 15;    // r = out-col row (d), ch over the 128 n's
            *(uint4*)&Out[base + (size_t)r * 1024 + n0 + ch * 8] = *(const uint4*)&CT[r * 136 + ch * 8];
        }
    }
}

// ---------------- K3: MFMA flash attention, M=32 Q-rows/wave ------------------
__global__ __launch_bounds__(256, 2) void k_attn2(const unsigned short* __restrict__ qb,
                                                  const unsigned short* __restrict__ kb,
                                                  const unsigned short* __restrict__ vtb,
                                                  unsigned short* __restrict__ ctxb) {
    __shared__ __align__(16) unsigned short sm[27136];
    // Ks [64][136] @0 ; Vt [128][72] @8704 ; Sp [4][32][72] @17920
    unsigned short* Ks = sm;
    unsigned short* Vt = sm + 8704;
    unsigned short* Sp = sm + 17920;

    const int tid = threadIdx.x;
    const int w = tid >> 6, lane = tid & 63;
    const int n16 = lane & 15, quad = lane >> 4;
    const int g = blockIdx.x;
    const int bh = g >> 3, tileq = g & 7;   // 128 bh x 8 tiles of 128 rows

    const unsigned short* Qp = qb + (size_t)bh * 131072 + (size_t)tileq * 128 * 128;
    const unsigned short* Kp = kb + (size_t)bh * 131072;
    const unsigned short* Vp = vtb + (size_t)bh * 131072;

    // Q fragments straight from global (A-layout: row=n16, k=quad*8+j)
    short8 qf[2][4];
#pragma unroll
    for (int rb = 0; rb < 2; ++rb)
#pragma unroll
        for (int dc = 0; dc < 4; ++dc)
            qf[rb][dc] = *(const short8*)&Qp[(size_t)(w * 32 + rb * 16 + n16) * 128 + dc * 32 + quad * 8];

    float mrun[2][4], lrun[2][4];
#pragma unroll
    for (int rb = 0; rb < 2; ++rb)
#pragma unroll
        for (int r = 0; r < 4; ++r) { mrun[rb][r] = -1e30f; lrun[rb][r] = 0.f; }
    f32x4 O[2][8];
#pragma unroll
    for (int rb = 0; rb < 2; ++rb)
#pragma unroll
        for (int dc = 0; dc < 8; ++dc) O[rb][dc] = (f32x4){0.f, 0.f, 0.f, 0.f};

    for (int kt = 0; kt < 16; ++kt) {
        __syncthreads();
#pragma unroll
        for (int p = 0; p < 4; ++p) {       // K tile 64x128
            int idx = tid + p * 256;
            int r = idx >> 4, ch = idx & 15;
            *(uint4*)&Ks[r * 136 + ch * 8] = *(const uint4*)&Kp[(size_t)(kt * 64 + r) * 128 + ch * 8];
        }
#pragma unroll
        for (int p = 0; p < 4; ++p) {       // V^T tile 128x64
            int idx = tid + p * 256;
            int r = idx >> 3, ch = idx & 7;
            *(uint4*)&Vt[r * 72 + ch * 8] = *(const uint4*)&Vp[(size_t)r * 1024 + kt * 64 + ch * 8];
        }
        __syncthreads();

        // S = Q K^T : 2 rowblocks x 4 keyblocks
        f32x4 S[2][4];
#pragma unroll
        for (int rb = 0; rb < 2; ++rb)
#pragma unroll
            for (int kc = 0; kc < 4; ++kc) S[rb][kc] = (f32x4){0.f, 0.f, 0.f, 0.f};
#pragma unroll
        for (int kc = 0; kc < 4; ++kc)
#pragma unroll
            for (int dc = 0; dc < 4; ++dc) {
                short8 kf = *(const short8*)&Ks[(kc * 16 + n16) * 136 + dc * 32 + quad * 8];
                S[0][kc] = __builtin_amdgcn_mfma_f32_16x16x32_bf16(qf[0][dc], kf, S[0][kc], 0, 0, 0);
                S[1][kc] = __builtin_amdgcn_mfma_f32_16x16x32_bf16(qf[1][dc], kf, S[1][kc], 0, 0, 0);
            }

        // online softmax; rows = quad*4+reg per rowblock
        float alpha[2][4];
#pragma unroll
        for (int rb = 0; rb < 2; ++rb)
#pragma unroll
            for (int reg = 0; reg < 4; ++reg) {
                float mx = fmaxf(fmaxf(S[rb][0][reg], S[rb][1][reg]), fmaxf(S[rb][2][reg], S[rb][3][reg]));
                mx = fmaxf(mx, __shfl_xor(mx, 1));
                mx = fmaxf(mx, __shfl_xor(mx, 2));
                mx = fmaxf(mx, __shfl_xor(mx, 4));
                mx = fmaxf(mx, __shfl_xor(mx, 8));
                float mnew = fmaxf(mrun[rb][reg], mx);
                alpha[rb][reg] = __expf(mrun[rb][reg] - mnew);
                mrun[rb][reg] = mnew;
                float ps = 0.f;
#pragma unroll
                for (int kc = 0; kc < 4; ++kc) {
                    float p = __expf(S[rb][kc][reg] - mnew);
                    S[rb][kc][reg] = p;
                    ps += p;
                }
                ps += __shfl_xor(ps, 1);
                ps += __shfl_xor(ps, 2);
                ps += __shfl_xor(ps, 4);
                ps += __shfl_xor(ps, 8);
                lrun[rb][reg] = lrun[rb][reg] * alpha[rb][reg] + ps;
            }
        // P -> per-wave LDS (bf16)
#pragma unroll
        for (int rb = 0; rb < 2; ++rb)
#pragma unroll
            for (int kc = 0; kc < 4; ++kc)
#pragma unroll
                for (int reg = 0; reg < 4; ++reg)
                    Sp[w * 2304 + (rb * 16 + quad * 4 + reg) * 72 + kc * 16 + n16] = f2bf(S[rb][kc][reg]);
        asm volatile("s_waitcnt lgkmcnt(0)" ::: "memory");

        // O = O*alpha + P V
#pragma unroll
        for (int rb = 0; rb < 2; ++rb)
#pragma unroll
            for (int dc = 0; dc < 8; ++dc)
#pragma unroll
                for (int reg = 0; reg < 4; ++reg) O[rb][dc][reg] *= alpha[rb][reg];
#pragma unroll
        for (int kchunk = 0; kchunk < 2; ++kchunk) {
            short8 pf0 = *(const short8*)&Sp[w * 2304 + (n16) * 72 + kchunk * 32 + quad * 8];
            short8 pf1 = *(const short8*)&Sp[w * 2304 + (16 + n16) * 72 + kchunk * 32 + quad * 8];
#pragma unroll
            for (int dc = 0; dc < 8; ++dc) {
                short8 vf = *(const short8*)&Vt[(dc * 16 + n16) * 72 + kchunk * 32 + quad * 8];
                O[0][dc] = __builtin_amdgcn_mfma_f32_16x16x32_bf16(pf0, vf, O[0][dc], 0, 0, 0);
                O[1][dc] = __builtin_amdgcn_mfma_f32_16x16x32_bf16(pf1, vf, O[1][dc], 0, 0, 0);
            }
        }
    }

    // epilogue: bounce bf16 ctx tile through LDS for coalesced store
    __syncthreads();
    unsigned short* Ct = sm;    // [128][136]
#pragma unroll
    for (int rb = 0; rb < 2; ++rb)
#pragma unroll
        for (int reg = 0; reg < 4; ++reg) {
            float inv = 1.f / lrun[rb][reg];
            int row = w * 32 + rb * 16 + quad * 4 + reg;
#pragma unroll
            for (int dc = 0; dc < 8; ++dc)
                Ct[row * 136 + dc * 16 + n16] = f2bf(O[rb][dc][reg] * inv);
        }
    __syncthreads();
    unsigned short* Outp = ctxb + (size_t)bh * 131072 + (size_t)tileq * 128 * 128;
#pragma unroll
    for (int p = 0; p < 8; ++p) {
        int idx = tid + p * 256;
        int r = idx >> 4, ch = idx & 15;
        *(uint4*)&Outp[(size_t)r * 128 + ch * 8] = *(const uint4*)&Ct[r * 136 + ch * 8];
    }
}

// ---------------- K4: h = ctx @ Wo + bo (M=16384, K=1024, N=128) -------------
__global__ __launch_bounds__(256) void k_proj_o(const unsigned short* __restrict__ Ctxb,
                                                const unsigned short* __restrict__ WoT,
                                                const float* __restrict__ bo,
                                                unsigned short* __restrict__ Hb) {
    __shared__ __align__(16) unsigned short sm[64 * 72 + 128 * 72];
    unsigned short* As = sm;            // [64][72]
    unsigned short* Bs = sm + 64 * 72;  // [128][72]
    int tid = threadIdx.x;
    int m0 = blockIdx.x * 64;
    int b = m0 >> 10, n0 = m0 & 1023;
    int w = tid >> 6, lane = tid & 63, n16 = lane & 15, quad = lane >> 4;
    int wr = (w & 1) * 32, wc = (w >> 1) * 64;
    f32x4 acc[2][4];
#pragma unroll
    for (int i = 0; i < 2; i++)
#pragma unroll
        for (int j = 0; j < 4; j++) acc[i][j] = (f32x4){0.f, 0.f, 0.f, 0.f};
    for (int kt = 0; kt < 16; ++kt) {
        __syncthreads();
        int hh = kt >> 1, d0 = (kt & 1) * 64;
#pragma unroll
        for (int p = 0; p < 2; ++p) {
            int idx = tid + p * 256;
            int r = idx >> 3, ch = idx & 7;
            *(uint4*)&As[r * 72 + ch * 8] =
                *(const uint4*)&Ctxb[((size_t)(b * 8 + hh) * 1024 + n0 + r) * 128 + d0 + ch * 8];
        }
#pragma unroll
        for (int p = 0; p < 4; ++p) {
            int idx = tid + p * 256;
            int r = idx >> 3, ch = idx & 7;
            *(uint4*)&Bs[r * 72 + ch * 8] = *(const uint4*)&WoT[(size_t)r * 1024 + kt * 64 + ch * 8];
        }
        __syncthreads();
#pragma unroll
        for (int kk = 0; kk < 2; ++kk) {
            short8 af0 = *(const short8*)&As[(wr + n16) * 72 + kk * 32 + quad * 8];
            short8 af1 = *(const short8*)&As[(wr + 16 + n16) * 72 + kk * 32 + quad * 8];
#pragma unroll
            for (int cb = 0; cb < 4; ++cb) {
                short8 bf = *(const short8*)&Bs[(wc + cb * 16 + n16) * 72 + kk * 32 + quad * 8];
                acc[0][cb] = __builtin_amdgcn_mfma_f32_16x16x32_bf16(af0, bf, acc[0][cb], 0, 0, 0);
                acc[1][cb] = __builtin_amdgcn_mfma_f32_16x16x32_bf16(af1, bf, acc[1][cb], 0, 0, 0);
            }
        }
    }
    __syncthreads();
    unsigned short* Ct = sm;    // bounce [64][136] (8704 <= 13824)
#pragma unroll
    for (int rb = 0; rb < 2; ++rb)
#pragma unroll
        for (int cb = 0; cb < 4; ++cb) {
            int col = wc + cb * 16 + n16;
            float bs = bo[col];
#pragma unroll
            for (int reg = 0; reg < 4; ++reg)
                Ct[(wr + rb * 16 + quad * 4 + reg) * 136 + col] = f2bf(acc[rb][cb][reg] + bs);
        }
    __syncthreads();
#pragma unroll
    for (int p = 0; p < 4; ++p) {
        int idx = tid + p * 256;
        int r = idx >> 4, ch = idx & 15;
        *(uint4*)&Hb[(size_t)(m0 + r) * 128 + ch * 8] = *(const uint4*)&Ct[r * 136 + ch * 8];
    }
}

// ---------------- K6: feat = relu(A_t @ hg), A_t fp32 cast inline ------------
__global__ __launch_bounds__(256) void k_at_gemm(const float* __restrict__ At,
                                                 const unsigned short* __restrict__ HgT,
                                                 float* __restrict__ Feat) {
    __shared__ __align__(16) unsigned short sm[64 * 72 + 128 * 72];
    unsigned short* As = sm;
    unsigned short* Bs = sm + 64 * 72;
    int tid = threadIdx.x;
    int bz = blockIdx.z;
    int m0 = blockIdx.x * 64;
    int w = tid >> 6, lane = tid & 63, n16 = lane & 15, quad = lane >> 4;
    int wr = (w & 1) * 32, wc = (w >> 1) * 64;
    f32x4 acc[2][4];
#pragma unroll
    for (int i = 0; i < 2; i++)
#pragma unroll
        for (int j = 0; j < 4; j++) acc[i][j] = (f32x4){0.f, 0.f, 0.f, 0.f};
    for (int kt = 0; kt < 16; ++kt) {
        __syncthreads();
#pragma unroll
        for (int p = 0; p < 2; ++p) {
            int idx = tid + p * 256;
            int r = idx >> 3, ch = idx & 7;
            const float* s = At + (size_t)bz * 1048576 + (size_t)(m0 + r) * 1024 + kt * 64 + ch * 8;
            float4 x = *(const float4*)s;
            float4 y = *(const float4*)(s + 4);
            uint4 o;
            o.x = pack2(x.x, x.y); o.y = pack2(x.z, x.w);
            o.z = pack2(y.x, y.y); o.w = pack2(y.z, y.w);
            *(uint4*)&As[r * 72 + ch * 8] = o;
        }
#pragma unroll
        for (int p = 0; p < 4; ++p) {
            int idx = tid + p * 256;
            int r = idx >> 3, ch = idx & 7;
            *(uint4*)&Bs[r * 72 + ch * 8] =
                *(const uint4*)&HgT[(size_t)bz * 131072 + (size_t)r * 1024 + kt * 64 + ch * 8];
        }
        __syncthreads();
#pragma unroll
        for (int kk = 0; kk < 2; ++kk) {
            short8 af0 = *(const short8*)&As[(wr + n16) * 72 + kk * 32 + quad * 8];
            short8 af1 = *(const short8*)&As[(wr + 16 + n16) * 72 + kk * 32 + quad * 8];
#pragma unroll
            for (int cb = 0; cb < 4; ++cb) {
                short8 bf = *(const short8*)&Bs[(wc + cb * 16 + n16) * 72 + kk * 32 + quad * 8];
                acc[0][cb] = __builtin_amdgcn_mfma_f32_16x16x32_bf16(af0, bf, acc[0][cb], 0, 0, 0);
                acc[1][cb] = __builtin_amdgcn_mfma_f32_16x16x32_bf16(af1, bf, acc[1][cb], 0, 0, 0);
            }
        }
    }
#pragma unroll
    for (int rb = 0; rb < 2; ++rb)
#pragma unroll
        for (int cb = 0; cb < 4; ++cb) {
            int col = wc + cb * 16 + n16;
#pragma unroll
            for (int reg = 0; reg < 4; ++reg) {
                int row = m0 + wr + rb * 16 + quad * 4 + reg;
                Feat[(size_t)bz * 131072 + (size_t)row * 128 + col] = fmaxf(acc[rb][cb][reg], 0.f);
            }
        }
}

// ---------------- K7: row normalize fp32 -> bf16 ------------------------------
__global__ __launch_bounds__(64) void k_norm(const float* __restrict__ F,
                                             unsigned short* __restrict__ Nb) {
    int row = blockIdx.x, tdx = threadIdx.x;
    const float* p = F + (size_t)row * 128;
    float2 xy = *(const float2*)&p[tdx * 2];
    float sum = xy.x + xy.y;
#pragma unroll
    for (int off = 32; off; off >>= 1) sum += __shfl_xor(sum, off);
    float mu = sum * (1.f / 128.f);
    float d0 = xy.x - mu, d1 = xy.y - mu;
    float sq = d0 * d0 + d1 * d1;
#pragma unroll
    for (int off = 32; off; off >>= 1) sq += __shfl_xor(sq, off);
    float sd = sqrtf(sq * (1.f / 127.f));
    float inv = 1.f / (sd + 1e-8f);
    ((unsigned*)Nb)[(size_t)row * 64 + tdx] = pack2(d0 * inv, d1 * inv);
}

// ---------------- K8: out[b] = norm @ norm^T / 128 (bf16 MFMA) ----------------
__global__ __launch_bounds__(256) void k_corr(const unsigned short* __restrict__ Nb,
                                              float* __restrict__ Out) {
    __shared__ __align__(16) unsigned short sm[2 * 128 * 136];
    unsigned short* Ar = sm;
    unsigned short* Br = sm + 128 * 136;
    int tid = threadIdx.x;
    int bz = blockIdx.z;
    int n0 = blockIdx.x * 128, m0 = blockIdx.y * 128;
    const unsigned short* base = Nb + (size_t)bz * 131072;
    int w = tid >> 6, lane = tid & 63, n16 = lane & 15, quad = lane >> 4;
#pragma unroll
    for (int p = 0; p < 8; ++p) {
        int idx = tid + p * 256;
        int r = idx >> 4, ch = idx & 15;
        *(uint4*)&Ar[r * 136 + ch * 8] = *(const uint4*)&base[(size_t)(n0 + r) * 128 + ch * 8];
        *(uint4*)&Br[r * 136 + ch * 8] = *(const uint4*)&base[(size_t)(m0 + r) * 128 + ch * 8];
    }
    __syncthreads();
    int wr = (w >> 1) * 64, wc = (w & 1) * 64;
    f32x4 acc[4][4];
#pragma unroll
    for (int i = 0; i < 4; i++)
#pragma unroll
        for (int j = 0; j < 4; j++) acc[i][j] = (f32x4){0.f, 0.f, 0.f, 0.f};
#pragma unroll
    for (int kk = 0; kk < 4; ++kk) {
        short8 af[4], bf[4];
#pragma unroll
        for (int rb = 0; rb < 4; ++rb)
            af[rb] = *(const short8*)&Ar[(wr + rb * 16 + n16) * 136 + kk * 32 + quad * 8];
#pragma unroll
        for (int cb = 0; cb < 4; ++cb)
            bf[cb] = *(const short8*)&Br[(wc + cb * 16 + n16) * 136 + kk * 32 + quad * 8];
#pragma unroll
        for (int rb = 0; rb < 4; ++rb)
#pragma unroll
            for (int cb = 0; cb < 4; ++cb)
                acc[rb][cb] = __builtin_amdgcn_mfma_f32_16x16x32_bf16(af[rb], bf[cb], acc[rb][cb], 0, 0, 0);
    }
#pragma unroll
    for (int rb = 0; rb < 4; ++rb)
#pragma unroll
        for (int cb = 0; cb < 4; ++cb)
#pragma unroll
            for (int reg = 0; reg < 4; ++reg) {
                int row = n0 + wr + rb * 16 + quad * 4 + reg;
                int col = m0 + wc + cb * 16 + n16;
                Out[(size_t)bz * 1048576 + (size_t)row * 1024 + col] = acc[rb][cb][reg] * 0.0078125f;
            }
}

extern "C" void kernel_launch(void* const* d_in, const int* in_sizes, int n_in,
                              void* d_out, int out_size, void* d_ws, size_t ws_size,
                              hipStream_t stream) {
    const float* A_t = (const float*)d_in[0];
    const float* F_c = (const float*)d_in[1];
    const int*   t   = (const int*)d_in[2];
    const float* Wq  = (const float*)d_in[3];
    const float* bq  = (const float*)d_in[4];
    const float* Wk  = (const float*)d_in[5];
    const float* bk  = (const float*)d_in[6];
    const float* Wv  = (const float*)d_in[7];
    const float* bv  = (const float*)d_in[8];
    const float* Wo  = (const float*)d_in[9];
    const float* bo  = (const float*)d_in[10];
    const float* Wg  = (const float*)d_in[11];
    float* out = (float*)d_out;
    char* ws = (char*)d_ws;

    unsigned short* cb   = (unsigned short*)(ws);                 //  4 MB
    unsigned short* qb   = (unsigned short*)(ws + 4194304);       // 33.5 MB
    unsigned short* kbuf = (unsigned short*)(ws + 37748736);
    unsigned short* vtb  = (unsigned short*)(ws + 71303168);
    unsigned short* ctxb = (unsigned short*)(ws + 104857600);
    unsigned short* hb   = (unsigned short*)(ws + 138412032);     //  4 MB
    unsigned short* hgT  = (unsigned short*)(ws + 142606336);     //  4 MB
    float*          feat = (float*)        (ws + 146800640);      //  8 MB
    unsigned short* nb   = (unsigned short*)(ws + 155189248);     //  4 MB
    unsigned short* WqT  = (unsigned short*)(ws + 159383552);
    unsigned short* WkT  = (unsigned short*)(ws + 159645696);
    unsigned short* WvT  = (unsigned short*)(ws + 159907840);
    unsigned short* WoT  = (unsigned short*)(ws + 160169984);
    unsigned short* WgT  = (unsigned short*)(ws + 160432128);

    const float qscale = 0.08838834764831845f;   // 1/sqrt(128)

    k_prep_w<<<528, 256, 0, stream>>>(Wq, Wk, Wv, Wo, Wg, WqT, WkT, WvT, WoT, WgT);
    k_embed<<<1024, 256, 0, stream>>>(F_c, t, cb);
    k_proj<<<dim3(128, 8), 256, 0, stream>>>(cb, WqT, bq, qb,   qscale, 0, 8);
    k_proj<<<dim3(128, 8), 256, 0, stream>>>(cb, WkT, bk, kbuf, 1.f,    0, 8);
    k_proj<<<dim3(128, 8), 256, 0, stream>>>(cb, WvT, bv, vtb,  1.f,    1, 8);
    k_attn2<<<1024, 256, 0, stream>>>(qb, kbuf, vtb, ctxb);
    k_proj_o<<<256, 256, 0, stream>>>(ctxb, WoT, bo, hb);
    k_proj<<<dim3(128, 1), 256, 0, stream>>>(hb, WgT, nullptr, hgT, 1.f, 1, 1);
    k_at_gemm<<<dim3(16, 1, 16), 256, 0, stream>>>(A_t, hgT, feat);
    k_norm<<<16384, 64, 0, stream>>>(feat, nb);
    k_corr<<<dim3(8, 8, 16), 256, 0, stream>>>(nb, out);
}